// Round 6
// baseline (2482.976 us; speedup 1.0000x reference)
//
#include <hip/hip_runtime.h>
#include <math.h>

#define Bn 256
#define Tn 300
#define Nn 512
#define NB 64
#define LDV 68   // stream/Vd pitch: breaks 16-row stride conflicts
#define LDA 65   // diag-Cholesky pitch

#define TOFF(i,j) ((size_t)((i)*NB)*Nn + (size_t)(j)*NB)

// ---- helpers (512-thread tile ops) ----------------------------------------
__device__ __forceinline__ void load_tile_f4(const float* __restrict__ g, int tid, float4 r[2]) {
#pragma unroll
  for (int t = 0; t < 2; t++) {
    int q = tid + 512 * t;          // f4 index 0..1023
    int row = q >> 4, c4 = q & 15;  // 64 rows x 16 float4
    r[t] = ((const float4*)(g + (size_t)row * Nn))[c4];
  }
}
__device__ __forceinline__ void store_stage(float* __restrict__ s, int tid, const float4 r[2]) {
#pragma unroll
  for (int t = 0; t < 2; t++) {
    int q = tid + 512 * t;
    int row = q >> 4, c4 = q & 15;
    *((float4*)(s + row * LDV + c4 * 4)) = r[t];
  }
}
// acc -= Arows · Brows^T (64-deep), 2x4 frag at (tr*2.., tc+16*..)
// unroll 2 (NOT full): full unroll spills past the 128-VGPR ceiling on
// 512-thread WGs (R1-R3: 10 GB scratch/dispatch). Verified fix in R4.
__device__ __forceinline__ void mm_nt_sub(const float* __restrict__ sa, const float* __restrict__ sb,
                                          int tr, int tc, float acc[2][4]) {
#pragma unroll 2
  for (int k = 0; k < NB; k += 4) {
    float4 av[2], bv[4];
#pragma unroll
    for (int i = 0; i < 2; i++) av[i] = *(const float4*)(sa + (tr * 2 + i) * LDV + k);
#pragma unroll
    for (int j = 0; j < 4; j++) bv[j] = *(const float4*)(sb + (tc + 16 * j) * LDV + k);
#pragma unroll
    for (int i = 0; i < 2; i++)
#pragma unroll
      for (int j = 0; j < 4; j++)
        acc[i][j] -= av[i].x * bv[j].x + av[i].y * bv[j].y + av[i].z * bv[j].z + av[i].w * bv[j].w;
  }
}

// K1: gamma[b,d] = sum_t x[b,t,d]*w[b,t]; Nsum[b] = sum_t w[b,t]
__global__ __launch_bounds__(256) void k_gamma(const float* __restrict__ x,
                                               const float* __restrict__ w,
                                               float* __restrict__ gamma,
                                               float* __restrict__ Nsum) {
  int b = blockIdx.x, tid = threadIdx.x;
  const float2* xb = (const float2*)(x + (size_t)b * Tn * Nn);
  const float* wb = w + b * Tn;
  float gx = 0.f, gy = 0.f, ns = 0.f;
#pragma unroll 4
  for (int t = 0; t < Tn; t++) {
    float wt = wb[t];
    ns += wt;
    float2 v = xb[(size_t)t * 256 + tid];
    gx += v.x * wt;
    gy += v.y * wt;
  }
  float2 g2; g2.x = gx; g2.y = gy;
  ((float2*)(gamma + b * Nn))[tid] = g2;
  if (tid == 0) Nsum[b] = ns;
}

// K2: C = diag(exp(0.5*Dw)) * chol_w, full store with explicit zeros below diag
__global__ __launch_bounds__(256) void k_prepC(const float* __restrict__ Dw,
                                               const float* __restrict__ cholw,
                                               float* __restrict__ C) {
  int r = blockIdx.x, tid = threadIdx.x;
  float s = expf(0.5f * Dw[r]);
  for (int c = tid; c < Nn; c += 256)
    C[r * Nn + c] = (c >= r) ? s * cholw[r * Nn + c] : 0.f;
}

// K3: CCT = C*C^T. Upper 32x32 tiles (136) + the 8 below-diagonal tiles adjacent
// to the 64x64 diagonal blocks (needed by k_factor's full-tile reads).
__global__ __launch_bounds__(256) void k_cct(const float* __restrict__ C,
                                             float* __restrict__ CCT) {
  __shared__ float Ci[32][33];
  __shared__ float Cj[32][33];
  int tid = threadIdx.x;
  int idx = blockIdx.x, ti = 0, tj;
  if (idx < 136) {
    while (idx >= 16 - ti) { idx -= 16 - ti; ti++; }
    tj = ti + idx;
  } else {                 // lower sub-tile of 64x64 diag block j: (2j+1, 2j)
    ti = 2 * (idx - 136) + 1;
    tj = ti - 1;
  }
  int i0 = ti * 32, j0 = tj * 32;
  int m0 = (i0 > j0) ? i0 : j0;
  float acc[4] = {0.f, 0.f, 0.f, 0.f};
  int r = tid >> 3, c0 = tid & 7;
  for (int kt = m0; kt < Nn; kt += 32) {  // C rows are zero left of the diagonal
    __syncthreads();
    for (int q = tid; q < 1024; q += 256) {
      int rr = q >> 5, cc = q & 31;
      Ci[rr][cc] = C[(size_t)(i0 + rr) * Nn + kt + cc];
      Cj[rr][cc] = C[(size_t)(j0 + rr) * Nn + kt + cc];
    }
    __syncthreads();
    for (int k = 0; k < 32; k++) {
      float a = Ci[r][k];
#pragma unroll
      for (int j = 0; j < 4; j++) acc[j] += a * Cj[c0 + 8 * j][k];
    }
  }
#pragma unroll
  for (int j = 0; j < 4; j++)
    CCT[(size_t)(i0 + r) * Nn + j0 + c0 + 8 * j] = acc[j];
}

// K4 (left-looking, fused trsm): per batch b, reverse-Cholesky S = CCT + Nb*I = U U^T.
// R6: 2 blocks/CU. LDS cut 133.5KB -> ~51.3KB: single LDS staging buffers
// (registers ra/rb already double-buffer the global->LDS path, so load latency
// stays hidden under the MM; costs 1 extra barrier/stage) and sAd unioned onto
// the B-staging buffer (disjoint lifetimes). With 2 independent blocks/CU, one
// block's MM phases fill the other's serial Cholesky/backsub/barrier stalls --
// the lockstep stall that R0->R5 occupancy changes couldn't touch.
__global__ __attribute__((amdgpu_waves_per_eu(4)))
__launch_bounds__(512) void k_factor(const float* __restrict__ CCT,
                                     const float* __restrict__ Nsum,
                                     float* __restrict__ AG) {
  const int b = blockIdx.x, tid = threadIdx.x;
  float* A = AG + (size_t)b * Nn * Nn;
  const float Nb = Nsum[b];
  __shared__ __align__(16) float sA[NB * LDV];
  __shared__ __align__(16) float sBd[NB * LDV];  // B staging; aliased as sAd (LDA pitch)
  __shared__ __align__(16) float sVd[NB * LDV];
  __shared__ float sdg[NB];
  float* sAd = sBd;                               // union: lifetimes disjoint
  const int tr = tid >> 4, tc = tid & 15;         // 32 row-groups x 16 col-lanes
  float4 ra[2], rb[2];

  for (int j = 7; j >= 0; j--) {
    const int nst = 7 - j;
    // ---------- diag tile: acc = CCT(j,j)+Nb*I - sum_k U(j,k)U(j,k)^T ----------
    float acc[2][4];
    {
      const float* T = CCT + TOFF(j, j);
#pragma unroll
      for (int i = 0; i < 2; i++) {
        const int r = tr * 2 + i;
#pragma unroll
        for (int jj = 0; jj < 4; jj++) {
          const int c = tc + 16 * jj;
          float v = T[(size_t)r * Nn + c];
          if (r == c) v += Nb;
          acc[i][jj] = v;
        }
      }
    }
    if (nst) load_tile_f4(A + TOFF(j, j + 1), tid, ra);
    __syncthreads();                  // prior readers of sA done
    if (nst) store_stage(sA, tid, ra);
    __syncthreads();
    for (int kk = 0; kk < nst; kk++) {
      if (kk + 1 < nst) load_tile_f4(A + TOFF(j, j + 2 + kk), tid, ra);
      mm_nt_sub(sA, sA, tr, tc, acc);
      __syncthreads();                // all waves done reading sA
      if (kk + 1 < nst) { store_stage(sA, tid, ra); __syncthreads(); }
    }
    // deposit to sAd (=sBd union; no readers in flight)
#pragma unroll
    for (int i = 0; i < 2; i++)
#pragma unroll
      for (int jj = 0; jj < 4; jj++)
        sAd[(tr * 2 + i) * LDA + tc + 16 * jj] = acc[i][jj];
    __syncthreads();
    // reverse Cholesky (upper, columns high->low), outer-product deferred-scale
    {
      const int jj = tid & 63, i0 = tid >> 6;  // i0 = wave id
      for (int c = NB - 1; c > 0; --c) {
        float invd = 1.0f / sAd[c * LDA + c];
        if (jj < c) {
          float t = sAd[jj * LDA + c] * invd;
          for (int i = i0; i <= jj; i += 8)
            sAd[i * LDA + jj] -= sAd[i * LDA + c] * t;
        }
        __syncthreads();
      }
      if (tid < NB) sdg[tid] = rsqrtf(sAd[tid * LDA + tid]);
      __syncthreads();
      for (int q = tid; q < NB * NB; q += 512) {
        int r = q >> 6, cc = q & 63;
        if (r <= cc) sAd[r * LDA + cc] *= sdg[cc];
      }
      __syncthreads();
    }
    // Vd = Ujj^-1: zero, then barrier-free per-thread column back-substitution
    for (int q = tid; q < NB * LDV; q += 512) sVd[q] = 0.f;
    __syncthreads();
    if (tid < NB) {
      const int c = tid;
      for (int r = c; r >= 0; r--) {
        float s2 = (r == c) ? 1.f : 0.f;
        for (int k = r + 1; k <= c; k++) s2 -= sAd[r * LDA + k] * sVd[k * LDV + c];
        sVd[r * LDV + c] = s2 / sAd[r * LDA + r];
      }
    }
    __syncthreads();
    // stash Vd in a dead lower-triangle tile for k_solve
    {
      const int vr = (j < 7) ? 7 : 6, vc = (j < 7) ? j : 0;
      float* Vt = A + TOFF(vr, vc);
      for (int q = tid; q < NB * NB; q += 512) {
        int r = q >> 6, c = q & 63;
        Vt[(size_t)r * Nn + c] = sVd[r * LDV + c];
      }
    }
    // ---------- off-diag tiles: U(i,j) = (CCT(i,j) - sum_k U(i,k)U(j,k)^T) Vd^T ----------
    for (int i = j - 1; i >= 0; i--) {
      float acc2[2][4];
      {
        const float* T = CCT + TOFF(i, j);
#pragma unroll
        for (int ii = 0; ii < 2; ii++)
#pragma unroll
          for (int jj = 0; jj < 4; jj++)
            acc2[ii][jj] = T[(size_t)(tr * 2 + ii) * Nn + tc + 16 * jj];
      }
      if (nst) {
        load_tile_f4(A + TOFF(i, j + 1), tid, ra);
        load_tile_f4(A + TOFF(j, j + 1), tid, rb);
      }
      __syncthreads();                // prior readers of sA/sBd done
      if (nst) { store_stage(sA, tid, ra); store_stage(sBd, tid, rb); }
      __syncthreads();
      for (int kk = 0; kk < nst; kk++) {
        if (kk + 1 < nst) {
          load_tile_f4(A + TOFF(i, j + 2 + kk), tid, ra);
          load_tile_f4(A + TOFF(j, j + 2 + kk), tid, rb);
        }
        mm_nt_sub(sA, sBd, tr, tc, acc2);
        __syncthreads();              // done reading sA/sBd
        if (kk + 1 < nst) { store_stage(sA, tid, ra); store_stage(sBd, tid, rb); __syncthreads(); }
      }
      // trsm via round trip: X = acc2 · Vd^T  (sA free after last MM barrier)
#pragma unroll
      for (int ii = 0; ii < 2; ii++)
#pragma unroll
        for (int jj = 0; jj < 4; jj++)
          sA[(tr * 2 + ii) * LDV + tc + 16 * jj] = acc2[ii][jj];
      __syncthreads();
      {
        float out[2][4] = {};
#pragma unroll 2
        for (int k = 0; k < NB; k += 4) {
          float4 av[2], bv[4];
#pragma unroll
          for (int ii = 0; ii < 2; ii++) av[ii] = *(const float4*)(sA + (tr * 2 + ii) * LDV + k);
#pragma unroll
          for (int jj = 0; jj < 4; jj++) bv[jj] = *(const float4*)(sVd + (tc + 16 * jj) * LDV + k);
#pragma unroll
          for (int ii = 0; ii < 2; ii++)
#pragma unroll
            for (int jj = 0; jj < 4; jj++)
              out[ii][jj] += av[ii].x * bv[jj].x + av[ii].y * bv[jj].y +
                             av[ii].z * bv[jj].z + av[ii].w * bv[jj].w;
        }
        float* X = A + TOFF(i, j);
#pragma unroll
        for (int ii = 0; ii < 2; ii++)
#pragma unroll
          for (int jj = 0; jj < 4; jj++)
            X[(size_t)(tr * 2 + ii) * Nn + tc + 16 * jj] = out[ii][jj];
      }
      // no trailing barrier: next phase opens with a pre-store barrier
    }
  }
}

// K5: per batch, solve U*G = C (G upper) in place over U; Vd read from stash.
// Same single-buffer 2-blocks/CU treatment: sA+sB+sVd = 51KB.
__global__ __attribute__((amdgpu_waves_per_eu(4)))
__launch_bounds__(512) void k_solve(const float* __restrict__ C,
                                    float* __restrict__ AG) {
  const int b = blockIdx.x, tid = threadIdx.x;
  float* A = AG + (size_t)b * Nn * Nn;
  __shared__ __align__(16) float sA[NB * LDV];
  __shared__ __align__(16) float sB[NB * LDV];
  __shared__ __align__(16) float sVd[NB * LDV];
  const int tr = tid >> 4, tc = tid & 15;
  float4 ra[2], rb[2];
  for (int R = 7; R >= 0; R--) {
    {
      const int vr = (R < 7) ? 7 : 6, vc = (R < 7) ? R : 0;
      const float* Vt = A + TOFF(vr, vc);
      __syncthreads();                // prev R's readers of sVd done
      for (int q = tid; q < NB * NB; q += 512) {
        int r = q >> 6, c = q & 63;
        sVd[r * LDV + c] = Vt[(size_t)r * Nn + c];
      }
      __syncthreads();
    }
    for (int J = 7; J >= R; J--) {
      const int nst = J - R;
      float acc[2][4];
      {
        const float* T = C + TOFF(R, J);
#pragma unroll
        for (int ii = 0; ii < 2; ii++)
#pragma unroll
          for (int jj = 0; jj < 4; jj++)
            acc[ii][jj] = T[(size_t)(tr * 2 + ii) * Nn + tc + 16 * jj];
      }
      if (nst) {
        load_tile_f4(A + TOFF(R, R + 1), tid, ra);
        load_tile_f4(A + TOFF(R + 1, J), tid, rb);
      }
      __syncthreads();                // prior readers of sA/sB done
      if (nst) { store_stage(sA, tid, ra); store_stage(sB, tid, rb); }
      __syncthreads();
      for (int kk = 0; kk < nst; kk++) {
        if (kk + 1 < nst) {
          load_tile_f4(A + TOFF(R, R + 2 + kk), tid, ra);
          load_tile_f4(A + TOFF(R + 2 + kk, J), tid, rb);
        }
        // acc -= U(R,K) * G(K,J)   (A·B: b-side scalar reads, conflict-free)
#pragma unroll 2
        for (int k = 0; k < NB; k += 4) {
          float a4[2][4];
#pragma unroll
          for (int ii = 0; ii < 2; ii++) {
            float4 t = *(const float4*)(sA + (tr * 2 + ii) * LDV + k);
            a4[ii][0] = t.x; a4[ii][1] = t.y; a4[ii][2] = t.z; a4[ii][3] = t.w;
          }
#pragma unroll
          for (int k2 = 0; k2 < 4; k2++) {
            float bb[4];
#pragma unroll
            for (int jj = 0; jj < 4; jj++) bb[jj] = sB[(k + k2) * LDV + tc + 16 * jj];
#pragma unroll
            for (int ii = 0; ii < 2; ii++)
#pragma unroll
              for (int jj = 0; jj < 4; jj++) acc[ii][jj] -= a4[ii][k2] * bb[jj];
          }
        }
        __syncthreads();              // done reading sA/sB
        if (kk + 1 < nst) { store_stage(sA, tid, ra); store_stage(sB, tid, rb); __syncthreads(); }
      }
      // round trip: temp -> sA; G(R,J) = Vd * temp
#pragma unroll
      for (int ii = 0; ii < 2; ii++)
#pragma unroll
        for (int jj = 0; jj < 4; jj++)
          sA[(tr * 2 + ii) * LDV + tc + 16 * jj] = acc[ii][jj];
      __syncthreads();
      {
        float out[2][4] = {};
#pragma unroll 2
        for (int k = 0; k < NB; k += 4) {
          float v4[2][4];
#pragma unroll
          for (int ii = 0; ii < 2; ii++) {
            float4 t = *(const float4*)(sVd + (tr * 2 + ii) * LDV + k);
            v4[ii][0] = t.x; v4[ii][1] = t.y; v4[ii][2] = t.z; v4[ii][3] = t.w;
          }
#pragma unroll
          for (int k2 = 0; k2 < 4; k2++) {
            float bb[4];
#pragma unroll
            for (int jj = 0; jj < 4; jj++) bb[jj] = sA[(k + k2) * LDV + tc + 16 * jj];
#pragma unroll
            for (int ii = 0; ii < 2; ii++)
#pragma unroll
              for (int jj = 0; jj < 4; jj++) out[ii][jj] += v4[ii][k2] * bb[jj];
          }
        }
        float* G = A + TOFF(R, J);
#pragma unroll
        for (int ii = 0; ii < 2; ii++)
#pragma unroll
          for (int jj = 0; jj < 4; jj++)
            G[(size_t)(tr * 2 + ii) * Nn + tc + 16 * jj] = out[ii][jj];
      }
      // no trailing barrier: next phase opens with a pre-store barrier
    }
  }
}

// K6: y = G*gamma, mu = G^T y, logvar = 2 log diag(G), chol = G/diag rows,
// zero strict lower. One row per wave; barrier-free shuffle reduce. 8 waves.
__global__ __launch_bounds__(512) void k_finish(const float* __restrict__ gam,
                                                float* __restrict__ mu,
                                                float* __restrict__ logvar,
                                                float* __restrict__ cholG) {
  int b = blockIdx.x, tid = threadIdx.x;
  float* A = cholG + (size_t)b * Nn * Nn;
  __shared__ float gsh[Nn];
  __shared__ float mup[8][Nn];
  for (int c = tid; c < Nn; c += 512) gsh[c] = gam[b * Nn + c];
  __syncthreads();
  int w = tid >> 6, l = tid & 63;
  float mua[8] = {0.f, 0.f, 0.f, 0.f, 0.f, 0.f, 0.f, 0.f};
  for (int i = w; i < Nn; i += 8) {
    const size_t rowo = (size_t)i * Nn;
    float v[8];
    float s = 0.f;
#pragma unroll
    for (int j = 0; j < 8; j++) {
      int c = (j << 6) + l;
      v[j] = A[rowo + c];
      if (c >= i) s += v[j] * gsh[c];
    }
#pragma unroll
    for (int off = 32; off > 0; off >>= 1) s += __shfl_xor(s, off, 64);
    float d = A[rowo + i];
    float rinv = 1.f / d;
    if (l == 0) logvar[b * Nn + i] = 2.f * logf(d);
#pragma unroll
    for (int j = 0; j < 8; j++) {
      int c = (j << 6) + l;
      if (c >= i) mua[j] += v[j] * s;
      float o = (c > i) ? v[j] * rinv : (c == i ? 1.f : 0.f);
      A[rowo + c] = o;
    }
  }
#pragma unroll
  for (int j = 0; j < 8; j++) mup[w][(j << 6) + l] = mua[j];
  __syncthreads();
  for (int c = tid; c < Nn; c += 512)
    mu[b * Nn + c] = mup[0][c] + mup[1][c] + mup[2][c] + mup[3][c] +
                     mup[4][c] + mup[5][c] + mup[6][c] + mup[7][c];
}

extern "C" void kernel_launch(void* const* d_in, const int* in_sizes, int n_in,
                              void* d_out, int out_size, void* d_ws, size_t ws_size,
                              hipStream_t stream) {
  const float* x = (const float*)d_in[0];
  const float* w = (const float*)d_in[1];
  const float* Dw = (const float*)d_in[2];
  const float* cholw = (const float*)d_in[3];
  float* out = (float*)d_out;
  float* mu = out;                  // [B,512]
  float* logvar = out + Bn * Nn;    // [B,512]
  float* chol = out + 2 * Bn * Nn;  // [B,512,512] scratch: U (+Vd stash) -> G -> final
  float* gamma = mu;                // consumed before mu written
  float* Nsum = logvar;             // consumed before logvar written
  float* Cm = (float*)d_ws;
  float* CCT = Cm + Nn * Nn;
  (void)in_sizes; (void)n_in; (void)out_size; (void)ws_size;

  k_gamma<<<Bn, 256, 0, stream>>>(x, w, gamma, Nsum);
  k_prepC<<<Nn, 256, 0, stream>>>(Dw, cholw, Cm);
  k_cct<<<144, 256, 0, stream>>>(Cm, CCT);
  k_factor<<<Bn, 512, 0, stream>>>(CCT, Nsum, chol);
  k_solve<<<Bn, 512, 0, stream>>>(Cm, chol);
  k_finish<<<Bn, 512, 0, stream>>>(gamma, mu, logvar, chol);
}

// Round 8
// 2373.587 us; speedup vs baseline: 1.0461x; 1.0461x over previous
//
#include <hip/hip_runtime.h>
#include <math.h>

#define Bn 256
#define Tn 300
#define Nn 512
#define NB 64
#define LDV 68   // stream/Vd pitch: breaks 16-row stride conflicts
#define LDA 65   // diag-Cholesky pitch

#define TOFF(i,j) ((size_t)((i)*NB)*Nn + (size_t)(j)*NB)

// ---- helpers (512-thread tile ops) ----------------------------------------
__device__ __forceinline__ void load_tile_f4(const float* __restrict__ g, int tid, float4 r[2]) {
#pragma unroll
  for (int t = 0; t < 2; t++) {
    int q = tid + 512 * t;          // f4 index 0..1023
    int row = q >> 4, c4 = q & 15;  // 64 rows x 16 float4
    r[t] = ((const float4*)(g + (size_t)row * Nn))[c4];
  }
}
__device__ __forceinline__ void store_stage(float* __restrict__ s, int tid, const float4 r[2]) {
#pragma unroll
  for (int t = 0; t < 2; t++) {
    int q = tid + 512 * t;
    int row = q >> 4, c4 = q & 15;
    *((float4*)(s + row * LDV + c4 * 4)) = r[t];
  }
}
// acc -= Arows · Brows^T (64-deep), 2x4 frag. unroll 2: full unroll spills
// past the 128-VGPR ceiling on 512-thread WGs (R1-R3: 10 GB scratch).
__device__ __forceinline__ void mm_nt_sub(const float* __restrict__ sa, const float* __restrict__ sb,
                                          int tr, int tc, float acc[2][4]) {
#pragma unroll 2
  for (int k = 0; k < NB; k += 4) {
    float4 av[2], bv[4];
#pragma unroll
    for (int i = 0; i < 2; i++) av[i] = *(const float4*)(sa + (tr * 2 + i) * LDV + k);
#pragma unroll
    for (int j = 0; j < 4; j++) bv[j] = *(const float4*)(sb + (tc + 16 * j) * LDV + k);
#pragma unroll
    for (int i = 0; i < 2; i++)
#pragma unroll
      for (int j = 0; j < 4; j++)
        acc[i][j] -= av[i].x * bv[j].x + av[i].y * bv[j].y + av[i].z * bv[j].z + av[i].w * bv[j].w;
  }
}
// paired NT: accA -= sa1·sb^T, accB -= sa2·sb^T -- B reads shared (1.0 B/flop)
__device__ __forceinline__ void mm_nt_sub2(const float* __restrict__ sa1, const float* __restrict__ sa2,
                                           const float* __restrict__ sb,
                                           int tr, int tc, float accA[2][4], float accB[2][4]) {
#pragma unroll 2
  for (int k = 0; k < NB; k += 4) {
    float4 a1[2], a2[2], bv[4];
#pragma unroll
    for (int i = 0; i < 2; i++) {
      a1[i] = *(const float4*)(sa1 + (tr * 2 + i) * LDV + k);
      a2[i] = *(const float4*)(sa2 + (tr * 2 + i) * LDV + k);
    }
#pragma unroll
    for (int j = 0; j < 4; j++) bv[j] = *(const float4*)(sb + (tc + 16 * j) * LDV + k);
#pragma unroll
    for (int i = 0; i < 2; i++)
#pragma unroll
      for (int j = 0; j < 4; j++) {
        accA[i][j] -= a1[i].x * bv[j].x + a1[i].y * bv[j].y + a1[i].z * bv[j].z + a1[i].w * bv[j].w;
        accB[i][j] -= a2[i].x * bv[j].x + a2[i].y * bv[j].y + a2[i].z * bv[j].z + a2[i].w * bv[j].w;
      }
  }
}
// paired NT-accumulate: o1 += t1·vd^T, o2 += t2·vd^T (shared Vd reads)
__device__ __forceinline__ void mm_nt_pos2(const float* __restrict__ t1, const float* __restrict__ t2,
                                           const float* __restrict__ vd, bool u2,
                                           int tr, int tc, float o1[2][4], float o2[2][4]) {
#pragma unroll 2
  for (int k = 0; k < NB; k += 4) {
    float4 a1[2], a2[2], bv[4];
#pragma unroll
    for (int i = 0; i < 2; i++) {
      a1[i] = *(const float4*)(t1 + (tr * 2 + i) * LDV + k);
      if (u2) a2[i] = *(const float4*)(t2 + (tr * 2 + i) * LDV + k);
    }
#pragma unroll
    for (int j = 0; j < 4; j++) bv[j] = *(const float4*)(vd + (tc + 16 * j) * LDV + k);
#pragma unroll
    for (int i = 0; i < 2; i++)
#pragma unroll
      for (int j = 0; j < 4; j++) {
        o1[i][j] += a1[i].x * bv[j].x + a1[i].y * bv[j].y + a1[i].z * bv[j].z + a1[i].w * bv[j].w;
        if (u2)
          o2[i][j] += a2[i].x * bv[j].x + a2[i].y * bv[j].y + a2[i].z * bv[j].z + a2[i].w * bv[j].w;
      }
  }
}
// paired A·B subtract (k_solve): acc1 -= sa·b1, acc2 -= sa·b2 -- A reads shared
__device__ __forceinline__ void mm_ab_sub2(const float* __restrict__ sa, const float* __restrict__ b1,
                                           const float* __restrict__ b2, bool u2,
                                           int tr, int tc, float acc1[2][4], float acc2[2][4]) {
#pragma unroll 2
  for (int k = 0; k < NB; k += 4) {
    float a4[2][4];
#pragma unroll
    for (int ii = 0; ii < 2; ii++) {
      float4 t = *(const float4*)(sa + (tr * 2 + ii) * LDV + k);
      a4[ii][0] = t.x; a4[ii][1] = t.y; a4[ii][2] = t.z; a4[ii][3] = t.w;
    }
#pragma unroll
    for (int k2 = 0; k2 < 4; k2++) {
      float bb1[4];
#pragma unroll
      for (int jj = 0; jj < 4; jj++) bb1[jj] = b1[(k + k2) * LDV + tc + 16 * jj];
#pragma unroll
      for (int ii = 0; ii < 2; ii++)
#pragma unroll
        for (int jj = 0; jj < 4; jj++) acc1[ii][jj] -= a4[ii][k2] * bb1[jj];
      if (u2) {
        float bb2[4];
#pragma unroll
        for (int jj = 0; jj < 4; jj++) bb2[jj] = b2[(k + k2) * LDV + tc + 16 * jj];
#pragma unroll
        for (int ii = 0; ii < 2; ii++)
#pragma unroll
          for (int jj = 0; jj < 4; jj++) acc2[ii][jj] -= a4[ii][k2] * bb2[jj];
      }
    }
  }
}
// paired Vd·temp (k_solve trsm): o1 = vd·t1, o2 = vd·t2 -- Vd reads shared
__device__ __forceinline__ void mm_vd2(const float* __restrict__ vd, const float* __restrict__ t1,
                                       const float* __restrict__ t2, bool u2,
                                       int tr, int tc, float o1[2][4], float o2[2][4]) {
#pragma unroll 2
  for (int k = 0; k < NB; k += 4) {
    float v4[2][4];
#pragma unroll
    for (int ii = 0; ii < 2; ii++) {
      float4 t = *(const float4*)(vd + (tr * 2 + ii) * LDV + k);
      v4[ii][0] = t.x; v4[ii][1] = t.y; v4[ii][2] = t.z; v4[ii][3] = t.w;
    }
#pragma unroll
    for (int k2 = 0; k2 < 4; k2++) {
      float bb1[4];
#pragma unroll
      for (int jj = 0; jj < 4; jj++) bb1[jj] = t1[(k + k2) * LDV + tc + 16 * jj];
#pragma unroll
      for (int ii = 0; ii < 2; ii++)
#pragma unroll
        for (int jj = 0; jj < 4; jj++) o1[ii][jj] += v4[ii][k2] * bb1[jj];
      if (u2) {
        float bb2[4];
#pragma unroll
        for (int jj = 0; jj < 4; jj++) bb2[jj] = t2[(k + k2) * LDV + tc + 16 * jj];
#pragma unroll
        for (int ii = 0; ii < 2; ii++)
#pragma unroll
          for (int jj = 0; jj < 4; jj++) o2[ii][jj] += v4[ii][k2] * bb2[jj];
      }
    }
  }
}

// K1: gamma[b,d] = sum_t x[b,t,d]*w[b,t]; Nsum[b] = sum_t w[b,t]
__global__ __launch_bounds__(256) void k_gamma(const float* __restrict__ x,
                                               const float* __restrict__ w,
                                               float* __restrict__ gamma,
                                               float* __restrict__ Nsum) {
  int b = blockIdx.x, tid = threadIdx.x;
  const float2* xb = (const float2*)(x + (size_t)b * Tn * Nn);
  const float* wb = w + b * Tn;
  float gx = 0.f, gy = 0.f, ns = 0.f;
#pragma unroll 4
  for (int t = 0; t < Tn; t++) {
    float wt = wb[t];
    ns += wt;
    float2 v = xb[(size_t)t * 256 + tid];
    gx += v.x * wt;
    gy += v.y * wt;
  }
  float2 g2; g2.x = gx; g2.y = gy;
  ((float2*)(gamma + b * Nn))[tid] = g2;
  if (tid == 0) Nsum[b] = ns;
}

// K2: C = diag(exp(0.5*Dw)) * chol_w, full store with explicit zeros below diag
__global__ __launch_bounds__(256) void k_prepC(const float* __restrict__ Dw,
                                               const float* __restrict__ cholw,
                                               float* __restrict__ C) {
  int r = blockIdx.x, tid = threadIdx.x;
  float s = expf(0.5f * Dw[r]);
  for (int c = tid; c < Nn; c += 256)
    C[r * Nn + c] = (c >= r) ? s * cholw[r * Nn + c] : 0.f;
}

// K3: CCT = C*C^T. Upper 32x32 tiles (136) + the 8 below-diagonal tiles adjacent
// to the 64x64 diagonal blocks (needed by k_factor's full-tile reads).
__global__ __launch_bounds__(256) void k_cct(const float* __restrict__ C,
                                             float* __restrict__ CCT) {
  __shared__ float Ci[32][33];
  __shared__ float Cj[32][33];
  int tid = threadIdx.x;
  int idx = blockIdx.x, ti = 0, tj;
  if (idx < 136) {
    while (idx >= 16 - ti) { idx -= 16 - ti; ti++; }
    tj = ti + idx;
  } else {                 // lower sub-tile of 64x64 diag block j: (2j+1, 2j)
    ti = 2 * (idx - 136) + 1;
    tj = ti - 1;
  }
  int i0 = ti * 32, j0 = tj * 32;
  int m0 = (i0 > j0) ? i0 : j0;
  float acc[4] = {0.f, 0.f, 0.f, 0.f};
  int r = tid >> 3, c0 = tid & 7;
  for (int kt = m0; kt < Nn; kt += 32) {  // C rows are zero left of the diagonal
    __syncthreads();
    for (int q = tid; q < 1024; q += 256) {
      int rr = q >> 5, cc = q & 31;
      Ci[rr][cc] = C[(size_t)(i0 + rr) * Nn + kt + cc];
      Cj[rr][cc] = C[(size_t)(j0 + rr) * Nn + kt + cc];
    }
    __syncthreads();
    for (int k = 0; k < 32; k++) {
      float a = Ci[r][k];
#pragma unroll
      for (int j = 0; j < 4; j++) acc[j] += a * Cj[c0 + 8 * j][k];
    }
  }
#pragma unroll
  for (int j = 0; j < 4; j++)
    CCT[(size_t)(i0 + r) * Nn + j0 + c0 + 8 * j] = acc[j];
}

// K4: per batch b, reverse-Cholesky S = CCT + Nb*I = U U^T, fused trsm.
// R8 = R7 resubmit (container infra failure, no data): R5 base (2255us) +
// PAIR-CHUNKING of off-diag tiles: all off-diags of column-block j share the
// same B-side U(j,k), so two A tiles per staged B cut MM LDS traffic
// 1.5 -> 1.0 B/flop, halve B staging and per-tile barriers. Diag stream stages
// in sB; sAd aliases sA1[0] (disjoint lifetimes) to keep LDS ~122KB.
__global__ __attribute__((amdgpu_waves_per_eu(2)))
__launch_bounds__(512) void k_factor(const float* __restrict__ CCT,
                                     const float* __restrict__ Nsum,
                                     float* __restrict__ AG) {
  const int b = blockIdx.x, tid = threadIdx.x;
  float* A = AG + (size_t)b * Nn * Nn;
  const float Nb = Nsum[b];
  __shared__ __align__(16) float sA1[2][NB * LDV];
  __shared__ __align__(16) float sA2[2][NB * LDV];
  __shared__ __align__(16) float sB[2][NB * LDV];
  __shared__ __align__(16) float sVd[NB * LDV];
  __shared__ float sdg[NB];
  float* sAd = &sA1[0][0];                 // alias; lifetime disjoint from staging
  const int tr = tid >> 4, tc = tid & 15;  // 32 row-groups x 16 col-lanes
  float4 ra1[2], ra2[2], rb[2];

  for (int j = 7; j >= 0; j--) {
    const int nst = 7 - j;
    // ---------- diag tile: acc = CCT(j,j)+Nb*I - sum_k U(j,k)U(j,k)^T ----------
    float acc[2][4];
    {
      const float* T = CCT + TOFF(j, j);
#pragma unroll
      for (int i = 0; i < 2; i++) {
        const int r = tr * 2 + i;
#pragma unroll
        for (int jj = 0; jj < 4; jj++) {
          const int c = tc + 16 * jj;
          float v = T[(size_t)r * Nn + c];
          if (r == c) v += Nb;
          acc[i][jj] = v;
        }
      }
    }
    if (nst) load_tile_f4(A + TOFF(j, j + 1), tid, ra1);
    __syncthreads();                       // prior readers of sB done
    if (nst) store_stage(sB[0], tid, ra1);
    __syncthreads();
    for (int kk = 0; kk < nst; kk++) {
      const int s = kk & 1;
      if (kk + 1 < nst) load_tile_f4(A + TOFF(j, j + 2 + kk), tid, ra1);
      mm_nt_sub(sB[s], sB[s], tr, tc, acc);
      if (kk + 1 < nst) store_stage(sB[s ^ 1], tid, ra1);
      __syncthreads();
    }
    // deposit to sAd (alias of sA1[0]; prior sA1 readers covered by syncs above)
#pragma unroll
    for (int i = 0; i < 2; i++)
#pragma unroll
      for (int jj = 0; jj < 4; jj++)
        sAd[(tr * 2 + i) * LDA + tc + 16 * jj] = acc[i][jj];
    __syncthreads();
    // reverse Cholesky (upper, columns high->low), outer-product deferred-scale
    {
      const int jj = tid & 63, i0 = tid >> 6;
      for (int c = NB - 1; c > 0; --c) {
        float invd = 1.0f / sAd[c * LDA + c];
        if (jj < c) {
          float t = sAd[jj * LDA + c] * invd;
          for (int i = i0; i <= jj; i += 8)
            sAd[i * LDA + jj] -= sAd[i * LDA + c] * t;
        }
        __syncthreads();
      }
      if (tid < NB) sdg[tid] = rsqrtf(sAd[tid * LDA + tid]);
      __syncthreads();
      for (int q = tid; q < NB * NB; q += 512) {
        int r = q >> 6, cc = q & 63;
        if (r <= cc) sAd[r * LDA + cc] *= sdg[cc];
      }
      __syncthreads();
    }
    // Vd = Ujj^-1: zero, then barrier-free per-thread column back-substitution
    for (int q = tid; q < NB * LDV; q += 512) sVd[q] = 0.f;
    __syncthreads();
    if (tid < NB) {
      const int c = tid;
      for (int r = c; r >= 0; r--) {
        float s2 = (r == c) ? 1.f : 0.f;
        for (int k = r + 1; k <= c; k++) s2 -= sAd[r * LDA + k] * sVd[k * LDV + c];
        sVd[r * LDV + c] = s2 / sAd[r * LDA + r];
      }
    }
    __syncthreads();
    // stash Vd in a dead lower-triangle tile for k_solve
    {
      const int vr = (j < 7) ? 7 : 6, vc = (j < 7) ? j : 0;
      float* Vt = A + TOFF(vr, vc);
      for (int q = tid; q < NB * NB; q += 512) {
        int r = q >> 6, c = q & 63;
        Vt[(size_t)r * Nn + c] = sVd[r * LDV + c];
      }
    }
    // ---------- off-diag tiles, PAIRED: U(i,j) = (CCT(i,j) - sum U·U^T) Vd^T ----
    int i = j - 1;
    while (i >= 0) {
      const bool two = (i >= 1);
      float accA[2][4], accB[2][4];
      {
        const float* Ta = CCT + TOFF(i, j);
        const float* Tb = two ? (CCT + TOFF(i - 1, j)) : Ta;
#pragma unroll
        for (int ii = 0; ii < 2; ii++)
#pragma unroll
          for (int jj = 0; jj < 4; jj++) {
            accA[ii][jj] = Ta[(size_t)(tr * 2 + ii) * Nn + tc + 16 * jj];
            accB[ii][jj] = two ? Tb[(size_t)(tr * 2 + ii) * Nn + tc + 16 * jj] : 0.f;
          }
      }
      if (nst) {
        load_tile_f4(A + TOFF(i, j + 1), tid, ra1);
        if (two) load_tile_f4(A + TOFF(i - 1, j + 1), tid, ra2);
        load_tile_f4(A + TOFF(j, j + 1), tid, rb);
      }
      __syncthreads();                     // prior readers of sA1/sA2/sB/sAd done
      if (nst) {
        store_stage(sA1[0], tid, ra1);
        if (two) store_stage(sA2[0], tid, ra2);
        store_stage(sB[0], tid, rb);
      }
      __syncthreads();
      for (int kk = 0; kk < nst; kk++) {
        const int s = kk & 1;
        if (kk + 1 < nst) {
          load_tile_f4(A + TOFF(i, j + 2 + kk), tid, ra1);
          if (two) load_tile_f4(A + TOFF(i - 1, j + 2 + kk), tid, ra2);
          load_tile_f4(A + TOFF(j, j + 2 + kk), tid, rb);
        }
        if (two) mm_nt_sub2(sA1[s], sA2[s], sB[s], tr, tc, accA, accB);
        else     mm_nt_sub(sA1[s], sB[s], tr, tc, accA);
        if (kk + 1 < nst) {
          store_stage(sA1[s ^ 1], tid, ra1);
          if (two) store_stage(sA2[s ^ 1], tid, ra2);
          store_stage(sB[s ^ 1], tid, rb);
        }
        __syncthreads();
      }
      // trsm pair via round trip: X = acc · Vd^T
#pragma unroll
      for (int ii = 0; ii < 2; ii++)
#pragma unroll
        for (int jj = 0; jj < 4; jj++) {
          sA1[0][(tr * 2 + ii) * LDV + tc + 16 * jj] = accA[ii][jj];
          if (two) sA2[0][(tr * 2 + ii) * LDV + tc + 16 * jj] = accB[ii][jj];
        }
      __syncthreads();
      {
        float oA[2][4] = {}, oB[2][4] = {};
        mm_nt_pos2(sA1[0], sA2[0], sVd, two, tr, tc, oA, oB);
        float* Xa = A + TOFF(i, j);
#pragma unroll
        for (int ii = 0; ii < 2; ii++)
#pragma unroll
          for (int jj = 0; jj < 4; jj++)
            Xa[(size_t)(tr * 2 + ii) * Nn + tc + 16 * jj] = oA[ii][jj];
        if (two) {
          float* Xb = A + TOFF(i - 1, j);
#pragma unroll
          for (int ii = 0; ii < 2; ii++)
#pragma unroll
            for (int jj = 0; jj < 4; jj++)
              Xb[(size_t)(tr * 2 + ii) * Nn + tc + 16 * jj] = oB[ii][jj];
        }
      }
      // no trailing barrier: next phase opens with a pre-store barrier
      i -= 2;
    }
  }
}

// K5: per batch, solve U*G = C (G upper) in place over U; Vd from stash.
// PAIRED columns (J, J-1) share the A-side U(R,K) stage. Race-safe: column J
// reads only tiles (R,K<=J) and writes descend in J within the block.
__global__ __attribute__((amdgpu_waves_per_eu(2)))
__launch_bounds__(512) void k_solve(const float* __restrict__ C,
                                    float* __restrict__ AG) {
  const int b = blockIdx.x, tid = threadIdx.x;
  float* A = AG + (size_t)b * Nn * Nn;
  __shared__ __align__(16) float sA[2][NB * LDV];
  __shared__ __align__(16) float sB1[2][NB * LDV];
  __shared__ __align__(16) float sB2[2][NB * LDV];
  __shared__ __align__(16) float sVd[NB * LDV];
  const int tr = tid >> 4, tc = tid & 15;
  float4 ra[2], rb1[2], rb2[2];
  for (int R = 7; R >= 0; R--) {
    {
      const int vr = (R < 7) ? 7 : 6, vc = (R < 7) ? R : 0;
      const float* Vt = A + TOFF(vr, vc);
      __syncthreads();                     // prev readers of sVd done
      for (int q = tid; q < NB * NB; q += 512) {
        int r = q >> 6, c = q & 63;
        sVd[r * LDV + c] = Vt[(size_t)r * Nn + c];
      }
      __syncthreads();
    }
    int J = 7;
    while (J >= R) {
      const bool two = (J - 1 >= R);
      const int nst1 = J - R;
      const int nst2 = J - 1 - R;          // only meaningful when two
      float acc1[2][4], acc2[2][4];
      {
        const float* T1 = C + TOFF(R, J);
        const float* T2 = two ? (C + TOFF(R, J - 1)) : T1;
#pragma unroll
        for (int ii = 0; ii < 2; ii++)
#pragma unroll
          for (int jj = 0; jj < 4; jj++) {
            acc1[ii][jj] = T1[(size_t)(tr * 2 + ii) * Nn + tc + 16 * jj];
            acc2[ii][jj] = two ? T2[(size_t)(tr * 2 + ii) * Nn + tc + 16 * jj] : 0.f;
          }
      }
      if (nst1) {
        load_tile_f4(A + TOFF(R, R + 1), tid, ra);
        load_tile_f4(A + TOFF(R + 1, J), tid, rb1);
        if (two && nst2 > 0) load_tile_f4(A + TOFF(R + 1, J - 1), tid, rb2);
      }
      __syncthreads();                     // prior readers of sA/sB1/sB2 done
      if (nst1) {
        store_stage(sA[0], tid, ra);
        store_stage(sB1[0], tid, rb1);
        if (two && nst2 > 0) store_stage(sB2[0], tid, rb2);
      }
      __syncthreads();
      for (int kk = 0; kk < nst1; kk++) {
        const int s = kk & 1;
        if (kk + 1 < nst1) {
          load_tile_f4(A + TOFF(R, R + 2 + kk), tid, ra);
          load_tile_f4(A + TOFF(R + 2 + kk, J), tid, rb1);
          if (two && kk + 1 < nst2) load_tile_f4(A + TOFF(R + 2 + kk, J - 1), tid, rb2);
        }
        mm_ab_sub2(sA[s], sB1[s], sB2[s], two && (kk < nst2), tr, tc, acc1, acc2);
        if (kk + 1 < nst1) {
          store_stage(sA[s ^ 1], tid, ra);
          store_stage(sB1[s ^ 1], tid, rb1);
          if (two && kk + 1 < nst2) store_stage(sB2[s ^ 1], tid, rb2);
        }
        __syncthreads();
      }
      // trsm pair: temp -> sB1[0]/sB2[0]; G = Vd * temp
#pragma unroll
      for (int ii = 0; ii < 2; ii++)
#pragma unroll
        for (int jj = 0; jj < 4; jj++) {
          sB1[0][(tr * 2 + ii) * LDV + tc + 16 * jj] = acc1[ii][jj];
          if (two) sB2[0][(tr * 2 + ii) * LDV + tc + 16 * jj] = acc2[ii][jj];
        }
      __syncthreads();
      {
        float o1[2][4] = {}, o2[2][4] = {};
        mm_vd2(sVd, sB1[0], sB2[0], two, tr, tc, o1, o2);
        float* G1 = A + TOFF(R, J);
#pragma unroll
        for (int ii = 0; ii < 2; ii++)
#pragma unroll
          for (int jj = 0; jj < 4; jj++)
            G1[(size_t)(tr * 2 + ii) * Nn + tc + 16 * jj] = o1[ii][jj];
        if (two) {
          float* G2 = A + TOFF(R, J - 1);
#pragma unroll
          for (int ii = 0; ii < 2; ii++)
#pragma unroll
            for (int jj = 0; jj < 4; jj++)
              G2[(size_t)(tr * 2 + ii) * Nn + tc + 16 * jj] = o2[ii][jj];
        }
      }
      // no trailing barrier: next phase opens with a pre-store barrier
      J -= 2;
    }
  }
}

// K6: y = G*gamma, mu = G^T y, logvar = 2 log diag(G), chol = G/diag rows,
// zero strict lower. One row per wave; barrier-free shuffle reduce. 8 waves.
__global__ __launch_bounds__(512) void k_finish(const float* __restrict__ gam,
                                                float* __restrict__ mu,
                                                float* __restrict__ logvar,
                                                float* __restrict__ cholG) {
  int b = blockIdx.x, tid = threadIdx.x;
  float* A = cholG + (size_t)b * Nn * Nn;
  __shared__ float gsh[Nn];
  __shared__ float mup[8][Nn];
  for (int c = tid; c < Nn; c += 512) gsh[c] = gam[b * Nn + c];
  __syncthreads();
  int w = tid >> 6, l = tid & 63;
  float mua[8] = {0.f, 0.f, 0.f, 0.f, 0.f, 0.f, 0.f, 0.f};
  for (int i = w; i < Nn; i += 8) {
    const size_t rowo = (size_t)i * Nn;
    float v[8];
    float s = 0.f;
#pragma unroll
    for (int j = 0; j < 8; j++) {
      int c = (j << 6) + l;
      v[j] = A[rowo + c];
      if (c >= i) s += v[j] * gsh[c];
    }
#pragma unroll
    for (int off = 32; off > 0; off >>= 1) s += __shfl_xor(s, off, 64);
    float d = A[rowo + i];
    float rinv = 1.f / d;
    if (l == 0) logvar[b * Nn + i] = 2.f * logf(d);
#pragma unroll
    for (int j = 0; j < 8; j++) {
      int c = (j << 6) + l;
      if (c >= i) mua[j] += v[j] * s;
      float o = (c > i) ? v[j] * rinv : (c == i ? 1.f : 0.f);
      A[rowo + c] = o;
    }
  }
#pragma unroll
  for (int j = 0; j < 8; j++) mup[w][(j << 6) + l] = mua[j];
  __syncthreads();
  for (int c = tid; c < Nn; c += 512)
    mu[b * Nn + c] = mup[0][c] + mup[1][c] + mup[2][c] + mup[3][c] +
                     mup[4][c] + mup[5][c] + mup[6][c] + mup[7][c];
}

extern "C" void kernel_launch(void* const* d_in, const int* in_sizes, int n_in,
                              void* d_out, int out_size, void* d_ws, size_t ws_size,
                              hipStream_t stream) {
  const float* x = (const float*)d_in[0];
  const float* w = (const float*)d_in[1];
  const float* Dw = (const float*)d_in[2];
  const float* cholw = (const float*)d_in[3];
  float* out = (float*)d_out;
  float* mu = out;                  // [B,512]
  float* logvar = out + Bn * Nn;    // [B,512]
  float* chol = out + 2 * Bn * Nn;  // [B,512,512] scratch: U (+Vd stash) -> G -> final
  float* gamma = mu;                // consumed before mu written
  float* Nsum = logvar;             // consumed before logvar written
  float* Cm = (float*)d_ws;
  float* CCT = Cm + Nn * Nn;
  (void)in_sizes; (void)n_in; (void)out_size; (void)ws_size;

  k_gamma<<<Bn, 256, 0, stream>>>(x, w, gamma, Nsum);
  k_prepC<<<Nn, 256, 0, stream>>>(Dw, cholw, Cm);
  k_cct<<<144, 256, 0, stream>>>(Cm, CCT);
  k_factor<<<Bn, 512, 0, stream>>>(CCT, Nsum, chol);
  k_solve<<<Bn, 512, 0, stream>>>(Cm, chol);
  k_finish<<<Bn, 512, 0, stream>>>(gamma, mu, logvar, chol);
}